// Round 1
// baseline (111.201 us; speedup 1.0000x reference)
//
#include <hip/hip_runtime.h>

#define BB 4096
#define FF 39
#define DD 128
#define FIELD_DIM 10000

__global__ __launch_bounds__(256) void mixq_embed(
    const int* __restrict__ x,
    const float* __restrict__ arch_prob,
    const float* __restrict__ cb00, const int* __restrict__ i00,
    const float* __restrict__ cb10, const int* __restrict__ i10,
    const float* __restrict__ cb11, const int* __restrict__ i11,
    const float* __restrict__ cb12, const int* __restrict__ i12,
    const float* __restrict__ cb20, const int* __restrict__ i20,
    const float* __restrict__ cb21, const int* __restrict__ i21,
    const float* __restrict__ cb22, const int* __restrict__ i22,
    float* __restrict__ out)
{
    int tid  = blockIdx.x * blockDim.x + threadIdx.x;
    int item = tid >> 5;           // one (b,f) item per 32 lanes
    int lane = tid & 31;
    int d0   = lane << 2;          // each lane owns 4 consecutive d
    if (item >= BB * FF) return;

    int f  = item - (item / FF) * FF;     // item % FF
    int xg = x[item] + f * FIELD_DIM;

    const float* ap = arch_prob + f * 9;

    float4 acc = make_float4(0.f, 0.f, 0.f, 0.f);

#define DO_PAIR(cb, idx, M, col)                                              \
    do {                                                                      \
        const int plen = DD / (M);                                            \
        int k = (M) == 1 ? 0 : d0 / plen;                                     \
        int r = idx[(size_t)xg * (M) + k];                                    \
        float4 v = *reinterpret_cast<const float4*>((cb) + (size_t)r * DD + d0); \
        float s = ap[col];                                                    \
        acc.x += s * v.x;                                                     \
        acc.y += s * v.y;                                                     \
        acc.z += s * v.z;                                                     \
        acc.w += s * v.w;                                                     \
    } while (0)

    DO_PAIR(cb00, i00, 1, 0);
    DO_PAIR(cb10, i10, 1, 3);
    DO_PAIR(cb11, i11, 2, 4);
    DO_PAIR(cb12, i12, 4, 5);
    DO_PAIR(cb20, i20, 1, 6);
    DO_PAIR(cb21, i21, 2, 7);
    DO_PAIR(cb22, i22, 4, 8);
#undef DO_PAIR

    *reinterpret_cast<float4*>(out + (size_t)item * DD + d0) = acc;
}

extern "C" void kernel_launch(void* const* d_in, const int* in_sizes, int n_in,
                              void* d_out, int out_size, void* d_ws, size_t ws_size,
                              hipStream_t stream) {
    const int*   x  = (const int*)d_in[0];
    const float* ap = (const float*)d_in[1];
    const float* cb00 = (const float*)d_in[2];
    const int*   i00  = (const int*)d_in[3];
    const float* cb10 = (const float*)d_in[4];
    const int*   i10  = (const int*)d_in[5];
    const float* cb11 = (const float*)d_in[6];
    const int*   i11  = (const int*)d_in[7];
    const float* cb12 = (const float*)d_in[8];
    const int*   i12  = (const int*)d_in[9];
    const float* cb20 = (const float*)d_in[10];
    const int*   i20  = (const int*)d_in[11];
    const float* cb21 = (const float*)d_in[12];
    const int*   i21  = (const int*)d_in[13];
    const float* cb22 = (const float*)d_in[14];
    const int*   i22  = (const int*)d_in[15];
    float* out = (float*)d_out;

    const long long total_threads = (long long)BB * FF * 32;
    const int threads = 256;
    const int blocks = (int)((total_threads + threads - 1) / threads);

    mixq_embed<<<blocks, threads, 0, stream>>>(
        x, ap, cb00, i00, cb10, i10, cb11, i11, cb12, i12,
        cb20, i20, cb21, i21, cb22, i22, out);
}

// Round 2
// 90.183 us; speedup vs baseline: 1.2331x; 1.2331x over previous
//
#include <hip/hip_runtime.h>

#define BB 4096
#define FF 39
#define DD 128
#define FIELD_DIM 10000
#define NXCD 8

// Items are processed F-MAJOR (item = f*B + b) and blocks are chunked
// contiguously per XCD so each XCD's L2 only sees ~5 f's worth of idx
// tables (~3 MB, L2-resident) instead of all 23 MB.
__global__ __launch_bounds__(256) void mixq_embed(
    const int* __restrict__ x,
    const float* __restrict__ arch_prob,
    const float* __restrict__ cb00, const int* __restrict__ i00,
    const float* __restrict__ cb10, const int* __restrict__ i10,
    const float* __restrict__ cb11, const int* __restrict__ i11,
    const float* __restrict__ cb12, const int* __restrict__ i12,
    const float* __restrict__ cb20, const int* __restrict__ i20,
    const float* __restrict__ cb21, const int* __restrict__ i21,
    const float* __restrict__ cb22, const int* __restrict__ i22,
    float* __restrict__ out)
{
    // Bijective XCD chunking: grid size is a multiple of 8 (19968).
    const int nwg  = gridDim.x;
    const int cpx  = nwg >> 3;                       // blocks per XCD chunk
    const int orig = blockIdx.x;
    const int wgid = (orig & (NXCD - 1)) * cpx + (orig >> 3);

    const int tid  = wgid * 256 + (int)threadIdx.x;
    const int item = tid >> 5;                       // f-major item id
    const int lane = tid & 31;
    const int d0   = lane << 2;

    const int f = item >> 12;                        // item / 4096 (B=4096)
    const int b = item & (BB - 1);                   // item % 4096

    const int xg = x[b * FF + f] + f * FIELD_DIM;
    const float* ap = arch_prob + f * 9;

    float4 acc = make_float4(0.f, 0.f, 0.f, 0.f);

#define DO_PAIR(cb, idx, M, col)                                              \
    do {                                                                      \
        const int plen = DD / (M);                                            \
        int k = (M) == 1 ? 0 : d0 / plen;                                     \
        int r = idx[(size_t)xg * (M) + k];                                    \
        float4 v = *reinterpret_cast<const float4*>((cb) + (size_t)r * DD + d0); \
        float s = ap[col];                                                    \
        acc.x += s * v.x;                                                     \
        acc.y += s * v.y;                                                     \
        acc.z += s * v.z;                                                     \
        acc.w += s * v.w;                                                     \
    } while (0)

    DO_PAIR(cb00, i00, 1, 0);
    DO_PAIR(cb10, i10, 1, 3);
    DO_PAIR(cb11, i11, 2, 4);
    DO_PAIR(cb12, i12, 4, 5);
    DO_PAIR(cb20, i20, 1, 6);
    DO_PAIR(cb21, i21, 2, 7);
    DO_PAIR(cb22, i22, 4, 8);
#undef DO_PAIR

    // Non-temporal: output is write-once, keep it out of L2 so codebook/idx
    // lines stay resident.
    float* dst = out + ((size_t)b * FF + f) * DD + d0;
    __builtin_nontemporal_store(acc.x, dst + 0);
    __builtin_nontemporal_store(acc.y, dst + 1);
    __builtin_nontemporal_store(acc.z, dst + 2);
    __builtin_nontemporal_store(acc.w, dst + 3);
}

extern "C" void kernel_launch(void* const* d_in, const int* in_sizes, int n_in,
                              void* d_out, int out_size, void* d_ws, size_t ws_size,
                              hipStream_t stream) {
    const int*   x  = (const int*)d_in[0];
    const float* ap = (const float*)d_in[1];
    const float* cb00 = (const float*)d_in[2];
    const int*   i00  = (const int*)d_in[3];
    const float* cb10 = (const float*)d_in[4];
    const int*   i10  = (const int*)d_in[5];
    const float* cb11 = (const float*)d_in[6];
    const int*   i11  = (const int*)d_in[7];
    const float* cb12 = (const float*)d_in[8];
    const int*   i12  = (const int*)d_in[9];
    const float* cb20 = (const float*)d_in[10];
    const int*   i20  = (const int*)d_in[11];
    const float* cb21 = (const float*)d_in[12];
    const int*   i21  = (const int*)d_in[13];
    const float* cb22 = (const float*)d_in[14];
    const int*   i22  = (const int*)d_in[15];
    float* out = (float*)d_out;

    const long long total_threads = (long long)BB * FF * 32;
    const int threads = 256;
    const int blocks = (int)((total_threads + threads - 1) / threads); // 19968, %8==0

    mixq_embed<<<blocks, threads, 0, stream>>>(
        x, ap, cb00, i00, cb10, i10, cb11, i11, cb12, i12,
        cb20, i20, cb21, i21, cb22, i22, out);
}